// Round 1
// 217.880 us; speedup vs baseline: 1.0730x; 1.0730x over previous
//
#include <hip/hip_runtime.h>
#include <hip/hip_bf16.h>
#include <stdint.h>
#include <math.h>

#define BB 4
#define NN 2048
#define NFEAT 256
#define NHID 64
#define NHEADS 4
#define NCLASS 32
#define KK1 256
#define ALPHA 0.2f
#define LOG2E 1.4426950408889634f

typedef _Float16 f16x8 __attribute__((ext_vector_type(8)));
typedef _Float16 f16x4 __attribute__((ext_vector_type(4)));
typedef _Float16 h16x2 __attribute__((ext_vector_type(2)));
typedef float f32x4 __attribute__((ext_vector_type(4)));

__device__ __forceinline__ f16x8 ld8(const _Float16* p){
  f16x8 r;
  *(f16x4*)&r = *(const f16x4*)p;
  *((f16x4*)&r + 1) = *(const f16x4*)(p + 4);
  return r;
}

__device__ __forceinline__ h16x2 pk2(float a, float b){
  auto v = __builtin_amdgcn_cvt_pkrtz(a, b);   // __fp16 x2
  h16x2 r;
  __builtin_memcpy(&r, &v, sizeof(r));
  return r;
}

__device__ __forceinline__ float fexp2(float x){
#if __has_builtin(__builtin_amdgcn_exp2f)
  return __builtin_amdgcn_exp2f(x);
#else
  return exp2f(x);
#endif
}

// ---------------- K0: pack adj int32 -> bitmask + per-row count ---------
__global__ void __launch_bounds__(256) pack_adj(const int* __restrict__ adj,
                                                unsigned long long* __restrict__ bits,
                                                int* __restrict__ cnt){
  __shared__ int csum[4];
  int row = blockIdx.x;                       // b*N + i
  const int* arow = adj + (size_t)row * NN;
  int lane = threadIdx.x & 63, wv = threadIdx.x >> 6;
  int c = 0;
  #pragma unroll
  for (int it=0; it<NN/256; ++it){
    int j = it*256 + threadIdx.x;
    unsigned long long m = __ballot(arow[j] > 0);
    if (lane==0){ bits[(size_t)row*(NN/64) + it*4 + wv] = m; c += __popcll(m); }
  }
  if (lane==0) csum[wv] = c;
  __syncthreads();
  if (threadIdx.x==0) cnt[row] = csum[0]+csum[1]+csum[2]+csum[3];
}

// ---------------- K1: WhT(f16) = (x @ W)^T per head, f1l/f2l (log2e) ----
__global__ void __launch_bounds__(256) wh_proj2(const float* __restrict__ x,
        const float* __restrict__ W, const float* __restrict__ a1, const float* __restrict__ a2,
        _Float16* __restrict__ whT, float* __restrict__ f1l, float* __restrict__ f2l){
  __shared__ __align__(16) float xs[64*65];
  __shared__ float red1[4][64];
  __shared__ float red2[4][64];
  int bh = blockIdx.x >> 5;
  int i0 = (blockIdx.x & 31) * 64;
  int b = bh >> 2, h = bh & 3;
  int tid = threadIdx.x;
  int lane = tid & 63;
  int dbase = __builtin_amdgcn_readfirstlane(tid >> 6) * 16;
  float acc[16];
  #pragma unroll
  for (int dd=0; dd<16; ++dd) acc[dd] = 0.f;
  for (int kc=0; kc<4; ++kc){
    int kb = kc*64;
    __syncthreads();
    #pragma unroll
    for (int t=0; t<4; ++t){
      int row = t*16 + (tid>>4);
      int f4 = (tid&15)*4;
      float4 v = *(const float4*)(x + ((size_t)(b*NN + i0 + row))*NFEAT + kb + f4);
      xs[row*65 + f4 + 0] = v.x;
      xs[row*65 + f4 + 1] = v.y;
      xs[row*65 + f4 + 2] = v.z;
      xs[row*65 + f4 + 3] = v.w;
    }
    __syncthreads();
    const float* Wb = W + (size_t)h*NFEAT*NHID + (size_t)kb*NHID + dbase;
    #pragma unroll 4
    for (int f=0; f<64; ++f){
      float xv = xs[lane*65 + f];
      const float* wr = Wb + f*NHID;
      #pragma unroll
      for (int dd=0; dd<16; ++dd) acc[dd] = fmaf(xv, wr[dd], acc[dd]);
    }
  }
  float p1 = 0.f, p2 = 0.f;
  #pragma unroll
  for (int dd=0; dd<16; ++dd){
    int d = dbase + dd;
    whT[((size_t)bh*NHID + d)*NN + i0 + lane] = (_Float16)acc[dd];
    p1 = fmaf(acc[dd], a1[h*NHID + d], p1);
    p2 = fmaf(acc[dd], a2[h*NHID + d], p2);
  }
  int wv = tid >> 6;
  red1[wv][lane] = p1;
  red2[wv][lane] = p2;
  __syncthreads();
  if (tid < 64){
    float s1 = red1[0][tid]+red1[1][tid]+red1[2][tid]+red1[3][tid];
    float s2 = red2[0][tid]+red2[1][tid]+red2[2][tid]+red2[3][tid];
    f1l[(size_t)bh*NN + i0 + tid] = s1 * LOG2E;
    f2l[(size_t)bh*NN + i0 + tid] = s2 * LOG2E;
  }
}

// ---------- K2: h1 = elu(softmax(e) @ Wh), fused l, f16 MFMA ------------
// v2: single-barrier double-buffered pipeline. Next-chunk global loads are
// issued BEFORE the MFMA phase (latency hides under MFMA), LDS writes +
// weight exp2 land after it. PITCH=136 -> 16B-aligned ds_read_b128
// (bank stride 68 dwords => only free 2-way aliasing). Mask applied as
// bit-AND after exp2 (identical values: masked lanes become +0.0).
__global__ void __launch_bounds__(256) attn_l1(
        const unsigned long long* __restrict__ bits,
        const _Float16* __restrict__ whT,
        const float* __restrict__ f1l, const float* __restrict__ f2l,
        const int* __restrict__ cnt_in,
        float* __restrict__ dst){
  const int JC = 128, PITCH = 136;
  __shared__ __align__(16) _Float16 whs[2][64*PITCH];   // 2 x 17.0 KB
  __shared__ __align__(16) _Float16 wts[2][32*PITCH];   // 2 x 8.5 KB
  __shared__ float ils[32];
  int tile = blockIdx.x & 63;
  int bh = blockIdx.x >> 6;
  int b = bh >> 2, h = bh & 3;
  int i0 = tile*32;
  int tid = threadIdx.x;
  int lane = tid & 63, wv = tid >> 6;
  int q = lane >> 4, col = lane & 15;
  int r = tid >> 3, jg = (tid & 7) * 16;
  float f1r = f1l[(size_t)bh*NN + i0 + r];
  bool czr = (cnt_in[b*NN + i0 + r] == 0);
  const unsigned short* mrow = (const unsigned short*)(bits + ((size_t)(b*NN + i0 + r))*(NN/64));
  const float* f2p = f2l + (size_t)bh*NN + jg;
  const _Float16* whg = whT + (size_t)bh*NHID*NN;
  const _Float16* wsrc = whg + (size_t)(tid>>4)*NN + (tid&15)*8;
  float lacc = 0.f;
  f32x4 c0 = {0.f,0.f,0.f,0.f}, c1 = {0.f,0.f,0.f,0.f};
  uint4 vr0, vr1, vr2, vr3;
  float4 fa, fb, fc, fd;
  unsigned int m16 = 0;

  auto issue_loads = [&](int it){
    const _Float16* ws = wsrc + it*JC;
    vr0 = *(const uint4*)(ws);
    vr1 = *(const uint4*)(ws + 16*NN);
    vr2 = *(const uint4*)(ws + 32*NN);
    vr3 = *(const uint4*)(ws + 48*NN);
    const float* fp = f2p + it*JC;
    fa = *(const float4*)(fp);
    fb = *(const float4*)(fp+4);
    fc = *(const float4*)(fp+8);
    fd = *(const float4*)(fp+12);
    m16 = mrow[it*8 + (tid&7)];
  };

  auto stage = [&](int nb){
    _Float16* wb = &whs[nb][(tid>>4)*PITCH + (tid&15)*8];
    *(uint4*)(wb)             = vr0;
    *(uint4*)(wb + 16*PITCH)  = vr1;
    *(uint4*)(wb + 32*PITCH)  = vr2;
    *(uint4*)(wb + 48*PITCH)  = vr3;
    float fv[16] = {fa.x,fa.y,fa.z,fa.w, fb.x,fb.y,fb.z,fb.w,
                    fc.x,fc.y,fc.z,fc.w, fd.x,fd.y,fd.z,fd.w};
    h16x2 wp[8];
    #pragma unroll
    for (int p=0; p<8; ++p){
      float s0 = f1r + fv[2*p];
      float s1 = f1r + fv[2*p+1];
      float w0 = fexp2(fmaxf(s0, ALPHA*s0));
      float w1 = fexp2(fmaxf(s1, ALPHA*s1));
      // sign-extend bit (2p)/(2p+1) of m16 to an all-ones/zero mask
      unsigned mb0 = (unsigned)(((int)(m16 << (31 - 2*p))) >> 31);
      unsigned mb1 = (unsigned)(((int)(m16 << (30 - 2*p))) >> 31);
      w0 = __uint_as_float(__float_as_uint(w0) & mb0);
      w1 = __uint_as_float(__float_as_uint(w1) & mb1);
      lacc += w0 + w1;
      wp[p] = pk2(w0, w1);
    }
    if (__builtin_expect(czr, 0)){
      h16x2 one2 = {(_Float16)1.f, (_Float16)1.f};
      #pragma unroll
      for (int p=0; p<8; ++p) wp[p] = one2;
    }
    uint4* wdst = (uint4*)&wts[nb][r*PITCH + jg];
    wdst[0] = *(const uint4*)&wp[0];
    wdst[1] = *(const uint4*)&wp[4];
  };

  issue_loads(0);
  stage(0);
  __syncthreads();
  #pragma unroll 2
  for (int it=0; it<16; ++it){
    int cur = it & 1;
    if (it < 15) issue_loads(it+1);       // overlap HBM/L2 latency with MFMA
    #pragma unroll
    for (int ks=0; ks<4; ++ks){
      int kb = ks*32 + q*8;
      f16x8 a0  = *(const f16x8*)&wts[cur][col*PITCH + kb];
      f16x8 a1v = *(const f16x8*)&wts[cur][(16+col)*PITCH + kb];
      f16x8 bv  = *(const f16x8*)&whs[cur][(wv*16+col)*PITCH + kb];
      c0 = __builtin_amdgcn_mfma_f32_16x16x32_f16(a0, bv, c0, 0, 0, 0);
      c1 = __builtin_amdgcn_mfma_f32_16x16x32_f16(a1v, bv, c1, 0, 0, 0);
    }
    if (it < 15) stage(cur ^ 1);          // write NEXT buffers; no race with cur
    __syncthreads();                      // single barrier per chunk
  }
  lacc += __shfl_xor(lacc, 1, 64);
  lacc += __shfl_xor(lacc, 2, 64);
  lacc += __shfl_xor(lacc, 4, 64);
  if ((tid & 7) == 0) ils[r] = czr ? (1.0f/(float)NN) : 1.0f/lacc;
  __syncthreads();
  int dloc = wv*16 + col;
  #pragma unroll
  for (int mt=0; mt<2; ++mt){
    #pragma unroll
    for (int reg=0; reg<4; ++reg){
      int ir = mt*16 + q*4 + reg;
      float v = (mt==0 ? c0[reg] : c1[reg]) * ils[ir];
      v = v > 0.f ? v : expm1f(v);
      dst[((size_t)(b*NN + i0 + ir))*(NHEADS*NHID) + h*NHID + dloc] = v;
    }
  }
}

// ---------------- K3a: Wh2T(f16) = (h1 @ Wo)^T, f1ol/f2ol (log2e) -------
__global__ void __launch_bounds__(256) out_proj2(const float* __restrict__ h1,
        const float* __restrict__ Wo, const float* __restrict__ ao1, const float* __restrict__ ao2,
        _Float16* __restrict__ whT2, float* __restrict__ f1ol, float* __restrict__ f2ol){
  __shared__ __align__(16) float xs[64*65];
  __shared__ float red1[4][64];
  __shared__ float red2[4][64];
  int b = blockIdx.x >> 5;
  int i0 = (blockIdx.x & 31) * 64;
  int tid = threadIdx.x;
  int lane = tid & 63;
  int dbase = __builtin_amdgcn_readfirstlane(tid >> 6) * 8;
  float acc[8];
  #pragma unroll
  for (int dd=0; dd<8; ++dd) acc[dd] = 0.f;
  for (int kc=0; kc<4; ++kc){
    int kb = kc*64;
    __syncthreads();
    #pragma unroll
    for (int t=0; t<4; ++t){
      int row = t*16 + (tid>>4);
      int f4 = (tid&15)*4;
      float4 v = *(const float4*)(h1 + ((size_t)(b*NN + i0 + row))*256 + kb + f4);
      xs[row*65 + f4 + 0] = v.x;
      xs[row*65 + f4 + 1] = v.y;
      xs[row*65 + f4 + 2] = v.z;
      xs[row*65 + f4 + 3] = v.w;
    }
    __syncthreads();
    #pragma unroll 4
    for (int f=0; f<64; ++f){
      float xv = xs[lane*65 + f];
      const float* wr = Wo + (size_t)(kb+f)*NCLASS + dbase;
      #pragma unroll
      for (int dd=0; dd<8; ++dd) acc[dd] = fmaf(xv, wr[dd], acc[dd]);
    }
  }
  float p1 = 0.f, p2 = 0.f;
  #pragma unroll
  for (int dd=0; dd<8; ++dd){
    int d = dbase + dd;
    whT2[((size_t)b*NCLASS + d)*NN + i0 + lane] = (_Float16)acc[dd];
    p1 = fmaf(acc[dd], ao1[d], p1);
    p2 = fmaf(acc[dd], ao2[d], p2);
  }
  int wv = tid >> 6;
  red1[wv][lane] = p1;
  red2[wv][lane] = p2;
  __syncthreads();
  if (tid < 64){
    float s1 = red1[0][tid]+red1[1][tid]+red1[2][tid]+red1[3][tid];
    float s2 = red2[0][tid]+red2[1][tid]+red2[2][tid]+red2[3][tid];
    f1ol[(size_t)b*NN + i0 + tid] = s1 * LOG2E;
    f2ol[(size_t)b*NN + i0 + tid] = s2 * LOG2E;
  }
}

// ---------- K3b: layer-2 attention, GATHERED rows only, j-split x8 ------
// block = (b, kt, js): 32 gathered rows, j range [js*256, +256) (2 iters).
// Writes partial c [blk][32][32] and partial l [blk][32].
__global__ void __launch_bounds__(256) attn_l2(
        const unsigned long long* __restrict__ bits,
        const _Float16* __restrict__ whT2,
        const float* __restrict__ f1ol, const float* __restrict__ f2ol,
        const int* __restrict__ cnt_in, const int* __restrict__ oh,
        float* __restrict__ pc, float* __restrict__ pl){
  const int JC = 128, PITCH = 132;
  __shared__ __align__(16) _Float16 whs[32*PITCH];
  __shared__ __align__(16) _Float16 wts[32*PITCH];
  int blk = blockIdx.x;
  int js = blk & 7, kt = (blk>>3) & 7, b = blk >> 6;
  int tid = threadIdx.x;
  int lane = tid & 63, wv = tid >> 6;
  int q = lane >> 4, col = lane & 15;
  int r = tid >> 3, jg = (tid & 7) * 16;
  int row_i = oh[b*KK1 + kt*32 + r];
  float f1r = f1ol[b*NN + row_i];
  bool czr = (cnt_in[b*NN + row_i] == 0);
  const unsigned short* mrow = (const unsigned short*)(bits + ((size_t)(b*NN + row_i))*(NN/64));
  const float* f2p = f2ol + (size_t)b*NN;
  const _Float16* whg = whT2 + (size_t)b*NCLASS*NN;
  float lacc = 0.f;
  f32x4 c0 = {0.f,0.f,0.f,0.f};
  int mt = wv & 1, nt = wv >> 1;
  for (int ii=0; ii<2; ++ii){
    int it = js*2 + ii;
    __syncthreads();
    #pragma unroll
    for (int dd=0; dd<2; ++dd){
      int d = (tid>>4) + dd*16;
      int j8 = (tid&15)*8;
      uint4 v = *(const uint4*)(whg + (size_t)d*NN + it*JC + j8);
      uint2* w2 = (uint2*)&whs[d*PITCH + j8];
      w2[0] = uint2{v.x, v.y};
      w2[1] = uint2{v.z, v.w};
    }
    {
      unsigned int m16 = mrow[it*8 + (tid&7)];
      const float* fp = f2p + it*JC + jg;
      float4 fa = *(const float4*)(fp);
      float4 fb = *(const float4*)(fp+4);
      float4 fc = *(const float4*)(fp+8);
      float4 fd = *(const float4*)(fp+12);
      float fv[16] = {fa.x,fa.y,fa.z,fa.w, fb.x,fb.y,fb.z,fb.w,
                      fc.x,fc.y,fc.z,fc.w, fd.x,fd.y,fd.z,fd.w};
      h16x2 wp[8];
      #pragma unroll
      for (int p=0; p<8; ++p){
        float s0 = f1r + fv[2*p];
        float s1 = f1r + fv[2*p+1];
        s0 = (m16 & (1u<<(2*p)))   ? s0 : -1e5f;
        s1 = (m16 & (1u<<(2*p+1))) ? s1 : -1e5f;
        float e0 = fmaxf(s0, ALPHA*s0);
        float e1 = fmaxf(s1, ALPHA*s1);
        float w0 = exp2f(e0);
        float w1 = exp2f(e1);
        lacc += w0 + w1;
        wp[p] = pk2(w0, w1);
      }
      if (__builtin_expect(czr, 0)){
        h16x2 one2 = {(_Float16)1.f, (_Float16)1.f};
        #pragma unroll
        for (int p=0; p<8; ++p) wp[p] = one2;
        lacc += 16.f;
      }
      uint2* wdst = (uint2*)&wts[r*PITCH + jg];
      const uint2* wsrc = (const uint2*)&wp[0];
      wdst[0]=wsrc[0]; wdst[1]=wsrc[1]; wdst[2]=wsrc[2]; wdst[3]=wsrc[3];
    }
    __syncthreads();
    #pragma unroll
    for (int ks=0; ks<4; ++ks){
      int kb = ks*32 + q*8;
      f16x8 a0 = ld8(&wts[(mt*16+col)*PITCH + kb]);
      f16x8 bv = ld8(&whs[(nt*16+col)*PITCH + kb]);
      c0 = __builtin_amdgcn_mfma_f32_16x16x32_f16(a0, bv, c0, 0, 0, 0);
    }
  }
  lacc += __shfl_xor(lacc, 1, 64);
  lacc += __shfl_xor(lacc, 2, 64);
  lacc += __shfl_xor(lacc, 4, 64);
  if ((tid & 7) == 0) pl[blk*32 + r] = lacc;
  int dloc = nt*16 + col;
  #pragma unroll
  for (int reg=0; reg<4; ++reg){
    int ir = mt*16 + q*4 + reg;
    pc[(size_t)blk*1024 + ir*32 + dloc] = c0[reg];
  }
}

// ---------------- K4: combine partials + ELU + MLP ----------------------
__global__ void __launch_bounds__(256) classify2(const float* __restrict__ pc,
        const float* __restrict__ pl,
        const float* __restrict__ W1, const float* __restrict__ b1,
        const float* __restrict__ pw, const float* __restrict__ W2, const float* __restrict__ b2,
        float* __restrict__ out){
  __shared__ float efs[4][32];
  int wv = threadIdx.x >> 6;
  int lane = threadIdx.x & 63;
  int row = blockIdx.x*4 + wv;        // 0..B*K1-1
  int b = row >> 8, k = row & 255;
  int kt = k >> 5, r = k & 31;
  int base = (b*8 + kt)*8;
  if (lane < 32){
    float s = 0.f, l = 0.f;
    #pragma unroll
    for (int js=0; js<8; ++js){
      s += pc[(size_t)(base+js)*1024 + r*32 + lane];
      l += pl[(base+js)*32 + r];
    }
    float v = s / l;
    v = v > 0.f ? v : expm1f(v);
    efs[wv][lane] = v;
  }
  __syncthreads();
  const float* ef = efs[wv];
  int c = lane & 31;
  float y = b1[c];
  #pragma unroll 8
  for (int kk=0; kk<32; ++kk) y += ef[kk] * W1[kk*32 + c];
  y = y > 0.f ? y : pw[c]*y;
  float o0 = y * W2[c*2+0];
  float o1 = y * W2[c*2+1];
  #pragma unroll
  for (int o=16;o>0;o>>=1){ o0 += __shfl_xor(o0,o,64); o1 += __shfl_xor(o1,o,64); }
  if (lane==0){ out[row*2+0] = o0 + b2[0]; out[row*2+1] = o1 + b2[1]; }
}

extern "C" void kernel_launch(void* const* d_in, const int* in_sizes, int n_in,
                              void* d_out, int out_size, void* d_ws, size_t ws_size,
                              hipStream_t stream) {
  const float* x    = (const float*)d_in[0];
  const int*   adj  = (const int*)  d_in[1];
  const int*   oh   = (const int*)  d_in[2];
  const float* W    = (const float*)d_in[3];
  const float* a1   = (const float*)d_in[4];
  const float* a2   = (const float*)d_in[5];
  const float* Wo   = (const float*)d_in[6];
  const float* ao1  = (const float*)d_in[7];
  const float* ao2  = (const float*)d_in[8];
  const float* W1   = (const float*)d_in[9];
  const float* b1   = (const float*)d_in[10];
  const float* pw   = (const float*)d_in[11];
  const float* W2   = (const float*)d_in[12];
  const float* b2   = (const float*)d_in[13];
  float* out = (float*)d_out;

  char* base = (char*)d_ws;
  size_t off = 0;
  auto alloc = [&](size_t bytes)->char*{
    char* p = base + off;
    off = (off + bytes + 255) & ~(size_t)255;
    return p;
  };
  unsigned long long* adjbits = (unsigned long long*)alloc((size_t)BB*NN*(NN/64)*8); // 2 MB
  int*   cnt1 = (int*)  alloc((size_t)BB*NN*4);
  _Float16* WhT  = (_Float16*)alloc((size_t)BB*NHEADS*NHID*NN*2);  // 4 MB, [bh][d][i]
  float* f1l  = (float*)alloc((size_t)BB*NHEADS*NN*4);
  float* f2l  = (float*)alloc((size_t)BB*NHEADS*NN*4);
  float* h1   = (float*)alloc((size_t)BB*NN*(NHEADS*NHID)*4);      // 8 MB
  _Float16* WhT2 = (_Float16*)alloc((size_t)BB*NCLASS*NN*2);       // 512 KB, [b][d][i]
  float* f1ol = (float*)alloc((size_t)BB*NN*4);
  float* f2ol = (float*)alloc((size_t)BB*NN*4);
  float* pc   = (float*)alloc((size_t)256*1024*4);                 // 1 MB partial c
  float* pl   = (float*)alloc((size_t)256*32*4);                   // partial l

  pack_adj<<<BB*NN, 256, 0, stream>>>(adj, adjbits, cnt1);
  wh_proj2<<<BB*NHEADS*(NN/64), 256, 0, stream>>>(x, W, a1, a2, WhT, f1l, f2l);
  attn_l1<<<BB*NHEADS*(NN/32), 256, 0, stream>>>(adjbits, WhT, f1l, f2l, cnt1, h1);
  out_proj2<<<BB*(NN/64), 256, 0, stream>>>(h1, Wo, ao1, ao2, WhT2, f1ol, f2ol);
  attn_l2<<<BB*8*8, 256, 0, stream>>>(adjbits, WhT2, f1ol, f2ol, cnt1, oh, pc, pl);
  classify2<<<(BB*KK1)/4, 256, 0, stream>>>(pc, pl, W1, b1, pw, W2, b2, out);
}